// Round 9
// baseline (782.419 us; speedup 1.0000x reference)
//
#include <hip/hip_runtime.h>

// ---------------------------------------------------------------------------
// GRU_13030930776564: bidirectional GRU, B=64, L=1024, DI=D=DO=256 (fp32 io).
//   P1: X  = bf16( inputs @ Wi + Wi_b )                        [65536 x 256]
//   P2: merged 3-GEMM kernel (grid 1536), A staged via global_load_lds with
//       XOR-swizzled source, LDS double-buffered.
//   R : 64 WGs x 512 thr, R1 schedule, INT8 MFMA (R8, verified absmax-neutral).
//       R9 residual cuts (dependency-graph only, no sync changes):
//        - u32 offset accumulators for x-prefetch + Hg store (+-256 elem/step,
//          SALU-selected increment) — kills per-step 64-bit addr mul-adds.
//        - exp2 args pre-scaled OFF the critical path: srqn=srq*(-log2e) per
//          column; cx*_s converted+scaled during the PREVIOUS step; hp2 =
//          hprev*2*log2e at step end. Gate chain = cvt->fma->exp2->rcp.
//        - MFMA K-chains split 2+2 (integer partial sums, exact) — halves
//          the dependent-MFMA latency on the path.
//       mfma_i32_16x16x64_i8: 16 MFMAs + 4 ds_read_b128 per wave per step;
//       h fp32 in regs, int8 (scale 127) in LDS; W per-column int8 (one-time
//       in-kernel quant). hb8 16B-aligned, parity stride 320B. Sync:
//       s_barrier + lgkmcnt(0) only (Hg store + prefetch stay in flight).
//   F : out = fp32( (Hf + Hb) @ Wo + Wo_b )  — proven gemm256 A2 path.
// ws layout (u16 elements, E = 64*1024*256): XX | XR | XU | Hf(=X) | Hb
// ---------------------------------------------------------------------------

typedef float   f32x4 __attribute__((ext_vector_type(4)));
typedef short   s16x8 __attribute__((ext_vector_type(8)));
typedef int     i32x4 __attribute__((ext_vector_type(4)));
typedef unsigned int u32;
typedef unsigned short u16;

#define LDP  264   // padded row stride for gemm256 At (u16 elems)

__device__ __forceinline__ u16 f2bf(float x) {
    u32 u = __float_as_uint(x);
    return (u16)((u + 0x7FFFu + ((u >> 16) & 1u)) >> 16);   // RNE, inputs never NaN
}
__device__ __forceinline__ float bflo(u32 u) { return __uint_as_float(u << 16); }
__device__ __forceinline__ float bfhi(u32 u) { return __uint_as_float(u & 0xFFFF0000u); }
__device__ __forceinline__ float bf2f(u16 v) { return __uint_as_float((u32)v << 16); }

__device__ __forceinline__ void bar_lgkm() {
    asm volatile("s_waitcnt lgkmcnt(0)" ::: "memory");
    __builtin_amdgcn_s_barrier();
    asm volatile("" ::: "memory");
}
__device__ __forceinline__ void bar_only() {
    asm volatile("" ::: "memory");
    __builtin_amdgcn_s_barrier();
    asm volatile("" ::: "memory");
}

#define GLD_LDS16(g, l) __builtin_amdgcn_global_load_lds( \
    (const __attribute__((address_space(1))) unsigned int*)(g), \
    (__attribute__((address_space(3))) unsigned int*)(l), 16, 0, 0)

// ---------------------------------------------------------------------------
// Generic K=256, N=256 GEMM (P1: f32 A in; F: bf16 A + A2 sum, f32 out).
// Register-prefetched strips (R6).
// ---------------------------------------------------------------------------
__global__ __launch_bounds__(256, 2)
void gemm256(const void* __restrict__ Asrc, int a_f32, const u16* __restrict__ A2,
             const float* __restrict__ W, const float* __restrict__ b1,
             const float* __restrict__ b2, void* __restrict__ Cdst, int c_f32, int M)
{
    __shared__ u16 At[32 * LDP];
    const int tid  = threadIdx.x;
    const int lane = tid & 63, wv = tid >> 6;
    const int quad = lane >> 4, n16 = lane & 15;

    s16x8 bw[4][8];
    #pragma unroll
    for (int nt = 0; nt < 4; ++nt) {
        const int col = wv * 64 + nt * 16 + n16;
        #pragma unroll
        for (int kt = 0; kt < 8; ++kt) {
            const int kb0 = kt * 32 + quad * 8;
            s16x8 f;
            #pragma unroll
            for (int j = 0; j < 8; ++j) f[j] = (short)f2bf(W[(kb0 + j) * 256 + col]);
            bw[nt][kt] = f;
        }
    }

    const int arow = tid >> 3, kb = (tid & 7) * 32;
    float av[32];
    const int nstrip = M >> 5;
    const int stride = (int)gridDim.x;

    auto load_strip = [&](int ss) __attribute__((always_inline)) {
        const long base = (long)(ss * 32 + arow) * 256 + kb;
        if (a_f32) {
            const float4* p = (const float4*)((const float*)Asrc + base);
            #pragma unroll
            for (int i = 0; i < 8; ++i) {
                float4 v = p[i];
                av[i*4+0] = v.x; av[i*4+1] = v.y; av[i*4+2] = v.z; av[i*4+3] = v.w;
            }
        } else {
            const uint4* p = (const uint4*)((const u16*)Asrc + base);
            #pragma unroll
            for (int i = 0; i < 4; ++i) {
                uint4 v = p[i];
                av[i*8+0] = bflo(v.x); av[i*8+1] = bfhi(v.x);
                av[i*8+2] = bflo(v.y); av[i*8+3] = bfhi(v.y);
                av[i*8+4] = bflo(v.z); av[i*8+5] = bfhi(v.z);
                av[i*8+6] = bflo(v.w); av[i*8+7] = bfhi(v.w);
            }
            if (A2) {
                const uint4* q = (const uint4*)(A2 + base);
                #pragma unroll
                for (int i = 0; i < 4; ++i) {
                    uint4 v = q[i];
                    av[i*8+0] += bflo(v.x); av[i*8+1] += bfhi(v.x);
                    av[i*8+2] += bflo(v.y); av[i*8+3] += bfhi(v.y);
                    av[i*8+4] += bflo(v.z); av[i*8+5] += bfhi(v.z);
                    av[i*8+6] += bflo(v.w); av[i*8+7] += bfhi(v.w);
                }
            }
        }
    };

    int s = (int)blockIdx.x;
    if (s < nstrip) load_strip(s);

    for (; s < nstrip; ) {
        bar_only();
        {
            u16 tmp[32];
            #pragma unroll
            for (int i = 0; i < 32; ++i) tmp[i] = f2bf(av[i]);
            s16x8* dst = (s16x8*)&At[arow * LDP + kb];
            #pragma unroll
            for (int i = 0; i < 4; ++i) dst[i] = *(const s16x8*)&tmp[i * 8];
        }
        bar_lgkm();

        const int snext = s + stride;
        if (snext < nstrip) load_strip(snext);

        f32x4 acc[2][4];
        #pragma unroll
        for (int mt = 0; mt < 2; ++mt)
            #pragma unroll
            for (int nt = 0; nt < 4; ++nt) acc[mt][nt] = f32x4{0.f, 0.f, 0.f, 0.f};
        #pragma unroll
        for (int kt = 0; kt < 8; ++kt) {
            const int ko = kt * 32 + quad * 8;
            const s16x8 a0 = *(const s16x8*)&At[(n16) * LDP + ko];
            const s16x8 a1 = *(const s16x8*)&At[(16 + n16) * LDP + ko];
            #pragma unroll
            for (int nt = 0; nt < 4; ++nt) {
                acc[0][nt] = __builtin_amdgcn_mfma_f32_16x16x32_bf16(a0, bw[nt][kt], acc[0][nt], 0, 0, 0);
                acc[1][nt] = __builtin_amdgcn_mfma_f32_16x16x32_bf16(a1, bw[nt][kt], acc[1][nt], 0, 0, 0);
            }
        }

        #pragma unroll
        for (int nt = 0; nt < 4; ++nt) {
            const int col = wv * 64 + nt * 16 + n16;
            const float bias = b1[col] + (b2 ? b2[col] : 0.0f);
            #pragma unroll
            for (int mt = 0; mt < 2; ++mt) {
                const int row0 = s * 32 + mt * 16 + quad * 4;
                #pragma unroll
                for (int r = 0; r < 4; ++r) {
                    const float v = acc[mt][nt][r] + bias;
                    const long idx = (long)(row0 + r) * 256 + col;
                    if (c_f32) ((float*)Cdst)[idx] = v;
                    else       ((u16*)Cdst)[idx]   = f2bf(v);
                }
            }
        }
        s = snext;
    }
}

// ---------------------------------------------------------------------------
// P2 merged: 3 GEMMs (XX/XR/XU) in one launch, grid 1536 (matrix = bid>>9).
// A staged via global_load_lds (XOR-swizzled source), LDS double-buffered.
// ---------------------------------------------------------------------------
__global__ __launch_bounds__(256, 2)
void gemm_p2(const u16* __restrict__ X,
             const float* __restrict__ W0, const float* __restrict__ W1, const float* __restrict__ W2,
             const float* __restrict__ bA0, const float* __restrict__ bA1, const float* __restrict__ bA2,
             const float* __restrict__ bB1, const float* __restrict__ bB2,
             u16* __restrict__ C0, u16* __restrict__ C1, u16* __restrict__ C2)
{
    __shared__ u16 At[2][32 * 256];     // 2 x 16 KiB, linear
    const int tid  = threadIdx.x;
    const int lane = tid & 63, wv = tid >> 6;
    const int quad = lane >> 4, n16 = lane & 15;

    const int m  = (int)blockIdx.x >> 9;
    const int s0 = (int)blockIdx.x & 511;
    const float* W  = (m == 0) ? W0 : ((m == 1) ? W1 : W2);
    const float* b1 = (m == 0) ? bA0 : ((m == 1) ? bA1 : bA2);
    const float* b2 = (m == 0) ? (const float*)nullptr : ((m == 1) ? bB1 : bB2);
    u16* C = (m == 0) ? C0 : ((m == 1) ? C1 : C2);

    s16x8 bw[4][8];
    #pragma unroll
    for (int nt = 0; nt < 4; ++nt) {
        const int col = wv * 64 + nt * 16 + n16;
        #pragma unroll
        for (int kt = 0; kt < 8; ++kt) {
            const int kb0 = kt * 32 + quad * 8;
            s16x8 f;
            #pragma unroll
            for (int j = 0; j < 8; ++j) f[j] = (short)f2bf(W[(kb0 + j) * 256 + col]);
            bw[nt][kt] = f;
        }
    }

    u32 myL[4];
    #pragma unroll
    for (int r = 0; r < 4; ++r) {
        const u32 p = ((u32)(wv * 4 + r) * 64 + (u32)lane) * 16;
        myL[r] = p ^ (((p >> 9) & 7u) << 4);
    }
    const u32 key   = ((u32)(n16 & 7)) << 4;
    const u32 base0 = (u32)n16 * 512 + (u32)quad * 16;
    const u32 base1 = base0 + 16 * 512;

    {
        const char* src = (const char*)(X + (long)s0 * 32 * 256);
        #pragma unroll
        for (int r = 0; r < 4; ++r)
            GLD_LDS16(src + myL[r], (char*)&At[0][0] + (u32)(wv * 4 + r) * 1024);
    }

    int cur = 0;
    for (int s = s0; s < 2048; s += 512) {
        asm volatile("s_waitcnt vmcnt(0)" ::: "memory");
        bar_only();

        const int snext = s + 512;
        if (snext < 2048) {
            const char* src = (const char*)(X + (long)snext * 32 * 256);
            #pragma unroll
            for (int r = 0; r < 4; ++r)
                GLD_LDS16(src + myL[r], (char*)&At[cur ^ 1][0] + (u32)(wv * 4 + r) * 1024);
        }

        const char* atc = (const char*)&At[cur][0];
        f32x4 acc[2][4];
        #pragma unroll
        for (int mt = 0; mt < 2; ++mt)
            #pragma unroll
            for (int nt = 0; nt < 4; ++nt) acc[mt][nt] = f32x4{0.f, 0.f, 0.f, 0.f};
        #pragma unroll
        for (int kt = 0; kt < 8; ++kt) {
            const s16x8 a0 = *(const s16x8*)(atc + (((base0 + (u32)kt * 64) ^ key)));
            const s16x8 a1 = *(const s16x8*)(atc + (((base1 + (u32)kt * 64) ^ key)));
            #pragma unroll
            for (int nt = 0; nt < 4; ++nt) {
                acc[0][nt] = __builtin_amdgcn_mfma_f32_16x16x32_bf16(a0, bw[nt][kt], acc[0][nt], 0, 0, 0);
                acc[1][nt] = __builtin_amdgcn_mfma_f32_16x16x32_bf16(a1, bw[nt][kt], acc[1][nt], 0, 0, 0);
            }
        }

        #pragma unroll
        for (int nt = 0; nt < 4; ++nt) {
            const int col = wv * 64 + nt * 16 + n16;
            const float bias = b1[col] + (b2 ? b2[col] : 0.0f);
            #pragma unroll
            for (int mt = 0; mt < 2; ++mt) {
                const int row0 = s * 32 + mt * 16 + quad * 4;
                #pragma unroll
                for (int r = 0; r < 4; ++r) {
                    const float v = acc[mt][nt][r] + bias;
                    C[(long)(row0 + r) * 256 + col] = f2bf(v);
                }
            }
        }
        cur ^= 1;
    }
}

// ---------------------------------------------------------------------------
// Recurrence — R1 schedule, INT8 MFMA, R9 residual cuts. 64 blocks x 512 thr.
// Wave w owns h-cols [w*32,w*32+32), both gates. mfma_i32_16x16x64_i8,
// K-chains split 2+2 (integer partial sums — exact). u32 offset accumulators
// for prefetch/store. exp2 args pre-scaled off-path (srqn per col; cx*_s
// converted during the previous step; hp2 at step end).
// One lgkm-only barrier per step; Hg store + x prefetch stay in flight.
// ---------------------------------------------------------------------------
__global__ __launch_bounds__(512, 2)
void gru_rec(const u16* __restrict__ XX, const u16* __restrict__ XR, const u16* __restrict__ XU,
             const float* __restrict__ Wr, const float* __restrict__ Wu,
             u16* __restrict__ Hf, u16* __restrict__ Hb)
{
    __shared__ __attribute__((aligned(16))) char hb8[2][2 * 320];  // [buf][parity*320+col]
    __shared__ float sdq[8][2][32];       // dequant scale [wave][gate][col]

    const int tid  = threadIdx.x;
    const int lane = tid & 63, wave = tid >> 6;
    const int quad = lane >> 4, n16 = lane & 15;
    const int wg  = blockIdx.x;
    const int dir = wg >> 5;             // 0 fwd, 1 bwd
    const int b0  = (wg & 31) * 2;       // two batches: b0, b0+1
    const int c0  = wave * 32;

    // ---- preload + per-column int8 quantize: aw[g][nt][kt] (B-operand) ----
    i32x4 aw[2][2][4];
    #pragma unroll
    for (int g = 0; g < 2; ++g) {
        const float* Wg = g ? Wu : Wr;
        #pragma unroll
        for (int nt = 0; nt < 2; ++nt) {
            const int col = c0 + nt * 16 + n16;
            float wv64[64];
            float amax = 0.f;
            #pragma unroll
            for (int kt = 0; kt < 4; ++kt)
                #pragma unroll
                for (int j = 0; j < 16; ++j) {
                    const float w = Wg[(kt * 64 + quad * 16 + j) * 256 + col];
                    wv64[kt * 16 + j] = w;
                    amax = fmaxf(amax, fabsf(w));
                }
            // column amax spans the 4 quads (lane ^16, ^32) -> butterfly max
            amax = fmaxf(amax, __shfl_xor(amax, 16));
            amax = fmaxf(amax, __shfl_xor(amax, 32));
            const float inv = 127.f / amax;
            #pragma unroll
            for (int kt = 0; kt < 4; ++kt) {
                u32 b[4];
                #pragma unroll
                for (int d = 0; d < 4; ++d) {
                    u32 v = 0;
                    #pragma unroll
                    for (int e = 0; e < 4; ++e) {
                        const int qi = (int)__builtin_rintf(wv64[kt * 16 + d * 4 + e] * inv);
                        v |= ((u32)(qi & 255u)) << (8 * e);
                    }
                    b[d] = v;
                }
                aw[g][nt][kt] = (i32x4){(int)b[0], (int)b[1], (int)b[2], (int)b[3]};
            }
            if (quad == 0) sdq[wave][g][nt * 16 + n16] = amax * (1.0f / 16129.f); // amax/127^2
        }
    }

    // elementwise identity: one (seq, col) per lane
    const int  eseq = lane >> 5;                 // 0..1  (acc reg index)
    const int  ecl  = lane & 31;                 // 0..31
    const int  ntb  = ecl >> 4;                  // which n-tile holds this col
    const int  gcol = c0 + ecl;                  // global h column
    const long xrow = (long)(b0 + eseq) * 1024;  // row base within [B*L]
    float hprev = 0.0f, hp2 = 0.0f;

    for (int i = tid; i < 2 * 320; i += 512) hb8[0][i] = 0;   // h(0) = 0

    u16* const Hg = dir ? Hb : Hf;

    // u32 element-offset accumulators (max offset 2^24-1): off_pf tracks the
    // prefetch row (t advances +-1/step, clamped by skipping the final add);
    // off_st tracks the store row (no clamp needed: last use is t=end).
    u32 off_pf = (u32)((xrow + (dir ? 1023 : 0)) * 256 + gcol);
    u32 off_st = off_pf;
    const int inc = dir ? -256 : 256;

    // x for step 0, converted + pre-scaled (off critical path thereafter)
    float cxx_s, cxr_s, cxu_s;
    {
        cxx_s = bf2f(XX[off_pf]) *  2.88539008f;
        cxr_s = bf2f(XR[off_pf]) * -1.44269504f;
        cxu_s = bf2f(XU[off_pf]) * -1.44269504f;
    }
    __syncthreads();
    const float srqn = sdq[wave][0][ecl] * -1.44269504f;   // dequant*(-log2e) folded
    const float suqn = sdq[wave][1][ecl] * -1.44269504f;

    auto stepbody = [&](int step, int pb) __attribute__((always_inline)) {
        // advance + issue next step's x prefetch (full step of latency slack)
        if (step < 1023) off_pf += (u32)inc;
        const u16 nxx = XX[off_pf], nxr = XR[off_pf], nxu = XU[off_pf];

        // ---- int8 matvecs: 4 ds_read_b128 + 16 MFMAs, chains split 2+2 ----
        const char* hin = &hb8[pb][0] + (n16 & 1) * 320;
        i32x4 a00 = (i32x4){0,0,0,0}, a01 = a00, a10 = a00, a11 = a00;
        i32x4 b00 = a00, b01 = a00, b10 = a00, b11 = a00;
        {
            const i32x4 hv0 = *(const i32x4*)(hin + 0 * 64 + quad * 16);
            const i32x4 hv1 = *(const i32x4*)(hin + 1 * 64 + quad * 16);
            const i32x4 hv2 = *(const i32x4*)(hin + 2 * 64 + quad * 16);
            const i32x4 hv3 = *(const i32x4*)(hin + 3 * 64 + quad * 16);
            a00 = __builtin_amdgcn_mfma_i32_16x16x64_i8(hv0, aw[0][0][0], a00, 0, 0, 0);
            a01 = __builtin_amdgcn_mfma_i32_16x16x64_i8(hv0, aw[0][1][0], a01, 0, 0, 0);
            a10 = __builtin_amdgcn_mfma_i32_16x16x64_i8(hv0, aw[1][0][0], a10, 0, 0, 0);
            a11 = __builtin_amdgcn_mfma_i32_16x16x64_i8(hv0, aw[1][1][0], a11, 0, 0, 0);
            b00 = __builtin_amdgcn_mfma_i32_16x16x64_i8(hv2, aw[0][0][2], b00, 0, 0, 0);
            b01 = __builtin_amdgcn_mfma_i32_16x16x64_i8(hv2, aw[0][1][2], b01, 0, 0, 0);
            b10 = __builtin_amdgcn_mfma_i32_16x16x64_i8(hv2, aw[1][0][2], b10, 0, 0, 0);
            b11 = __builtin_amdgcn_mfma_i32_16x16x64_i8(hv2, aw[1][1][2], b11, 0, 0, 0);
            a00 = __builtin_amdgcn_mfma_i32_16x16x64_i8(hv1, aw[0][0][1], a00, 0, 0, 0);
            a01 = __builtin_amdgcn_mfma_i32_16x16x64_i8(hv1, aw[0][1][1], a01, 0, 0, 0);
            a10 = __builtin_amdgcn_mfma_i32_16x16x64_i8(hv1, aw[1][0][1], a10, 0, 0, 0);
            a11 = __builtin_amdgcn_mfma_i32_16x16x64_i8(hv1, aw[1][1][1], a11, 0, 0, 0);
            b00 = __builtin_amdgcn_mfma_i32_16x16x64_i8(hv3, aw[0][0][3], b00, 0, 0, 0);
            b01 = __builtin_amdgcn_mfma_i32_16x16x64_i8(hv3, aw[0][1][3], b01, 0, 0, 0);
            b10 = __builtin_amdgcn_mfma_i32_16x16x64_i8(hv3, aw[1][0][3], b10, 0, 0, 0);
            b11 = __builtin_amdgcn_mfma_i32_16x16x64_i8(hv3, aw[1][1][3], b11, 0, 0, 0);
        }

        // ---- in-lane select + exact integer combine + dequant ----
        const int pri = ntb ? (eseq ? a01[1] + b01[1] : a01[0] + b01[0])
                            : (eseq ? a00[1] + b00[1] : a00[0] + b00[0]);
        const int pui = ntb ? (eseq ? a11[1] + b11[1] : a11[0] + b11[0])
                            : (eseq ? a10[1] + b10[1] : a10[0] + b10[0]);

        // ---- elementwise: cvt -> fma -> exp2 -> rcp per gate ----
        const float er   = __builtin_amdgcn_exp2f(fmaf((float)pri, srqn, cxr_s));
        const float rr   = __builtin_amdgcn_rcpf(1.0f + er);
        const float eu   = __builtin_amdgcn_exp2f(fmaf((float)pui, suqn, cxu_s));
        const float uu   = __builtin_amdgcn_rcpf(1.0f + eu);
        const float ec   = __builtin_amdgcn_exp2f(fmaf(rr, hp2, cxx_s));
        const float cand = 1.0f - 2.0f * __builtin_amdgcn_rcpf(1.0f + ec);
        hprev = cand + uu * (hprev - cand);

        // |hprev| < 1 -> rint(h*127) in [-127,127], no clamp needed
        hb8[pb ^ 1][eseq * 320 + gcol] = (char)(int)__builtin_rintf(hprev * 127.f);
        Hg[off_st] = f2bf(hprev);                       // persist bf16 (fire & forget)
        off_st += (u32)inc;

        // stage next step's constants (off the next step's critical path)
        hp2   = hprev * 2.88539008f;
        cxx_s = bf2f(nxx) *  2.88539008f;
        cxr_s = bf2f(nxr) * -1.44269504f;
        cxu_s = bf2f(nxu) * -1.44269504f;

        bar_lgkm();                                     // hb8[pb^1] visible; NO vmcnt drain
    };

    for (int sp = 0; sp < 512; ++sp) {
        stepbody(sp * 2,     0);
        stepbody(sp * 2 + 1, 1);
    }
}

// ---------------------------------------------------------------------------
extern "C" void kernel_launch(void* const* d_in, const int* in_sizes, int n_in,
                              void* d_out, int out_size, void* d_ws, size_t ws_size,
                              hipStream_t stream)
{
    const float* inputs = (const float*)d_in[0];
    const float* Wi_w = (const float*)d_in[1];
    const float* Wi_b = (const float*)d_in[2];
    const float* Wx_w = (const float*)d_in[3];
    const float* Wx_b = (const float*)d_in[4];
    const float* Ux_w = (const float*)d_in[5];
    const float* Ux_b = (const float*)d_in[6];
    const float* Rx_w = (const float*)d_in[7];
    const float* Rx_b = (const float*)d_in[8];
    const float* Wr_w = (const float*)d_in[9];
    const float* Wr_b = (const float*)d_in[10];
    const float* Wu_w = (const float*)d_in[11];
    const float* Wu_b = (const float*)d_in[12];
    const float* Wo_w = (const float*)d_in[13];
    const float* Wo_b = (const float*)d_in[14];

    const long E = 64L * 1024 * 256;
    u16* XX = (u16*)d_ws;
    u16* XR = XX + E;
    u16* XU = XR + E;
    u16* Hf = XU + E;      // also used as X (bf16) between P1 and P2 — dead before R writes it
    u16* Hb = Hf + E;
    u16* Xb = Hf;

    const int M = 64 * 1024;
    const dim3 gg(512), gb(256);

    // P1: X = inputs @ Wi + Wi_b
    hipLaunchKernelGGL(gemm256, gg, gb, 0, stream,
                       (const void*)inputs, 1, (const u16*)nullptr, Wi_w, Wi_b, (const float*)nullptr,
                       (void*)Xb, 0, M);
    // P2 (merged): XX = X@Wx + Wx_b ; XR = X@Ux + Ux_b + Wr_b ; XU = X@Rx + Rx_b + Wu_b
    hipLaunchKernelGGL(gemm_p2, dim3(1536), gb, 0, stream,
                       (const u16*)Xb,
                       Wx_w, Ux_w, Rx_w,
                       Wx_b, Ux_b, Rx_b,
                       Wr_b, Wu_b,
                       XX, XR, XU);
    // R: the sequential scan (both directions concurrently, 64 WGs)
    hipLaunchKernelGGL(gru_rec, dim3(64), dim3(512), 0, stream,
                       (const u16*)XX, (const u16*)XR, (const u16*)XU, Wr_w, Wu_w, Hf, Hb);
    // F: out = (Hf + Hb) @ Wo + Wo_b  (proven gemm256 A2 path)
    hipLaunchKernelGGL(gemm256, gg, gb, 0, stream,
                       (const void*)Hf, 0, (const u16*)Hb, Wo_w, Wo_b, (const float*)nullptr,
                       d_out, 1, M);
}

// Round 10
// 696.674 us; speedup vs baseline: 1.1231x; 1.1231x over previous
//
#include <hip/hip_runtime.h>

// ---------------------------------------------------------------------------
// GRU_13030930776564: bidirectional GRU, B=64, L=1024, DI=D=DO=256 (fp32 io).
//   P1: X  = bf16( inputs @ Wi + Wi_b )                        [65536 x 256]
//   P2: merged 3-GEMM kernel (grid 1536), A staged via global_load_lds with
//       XOR-swizzled source, LDS double-buffered.
//   R : 64 WGs x 512 thr, R1 schedule, INT8 MFMA — EXACT R8 code (462 us,
//       absmax-neutral). R9's dependency-graph edits regressed 19% and are
//       reverted; the compiler's own schedule of this body is the best
//       measured. Step ~1083cy vs ~510cy i8-MFMA floor; schedule/TLP/
//       conflict/pre-barrier levers all measured dead (R2-R5, R9).
//   F : R10: gemm_f — out = Hf@Wo + Hb@Wo + Wo_b via MFMA linearity
//       (f32 accumulate, >= accuracy of the bf16 pre-add path). Both
//       operands staged via global_load_lds (gemm_p2's proven swizzle),
//       single-buffered 32KB LDS; kills the bf16 unpack/add/repack VALU
//       staging tax on 64MB.
// ws layout (u16 elements, E = 64*1024*256): XX | XR | XU | Hf(=X) | Hb
// ---------------------------------------------------------------------------

typedef float   f32x4 __attribute__((ext_vector_type(4)));
typedef short   s16x8 __attribute__((ext_vector_type(8)));
typedef int     i32x4 __attribute__((ext_vector_type(4)));
typedef unsigned int u32;
typedef unsigned short u16;

#define LDP  264   // padded row stride for gemm256 At (u16 elems)

__device__ __forceinline__ u16 f2bf(float x) {
    u32 u = __float_as_uint(x);
    return (u16)((u + 0x7FFFu + ((u >> 16) & 1u)) >> 16);   // RNE, inputs never NaN
}
__device__ __forceinline__ float bflo(u32 u) { return __uint_as_float(u << 16); }
__device__ __forceinline__ float bfhi(u32 u) { return __uint_as_float(u & 0xFFFF0000u); }
__device__ __forceinline__ float bf2f(u16 v) { return __uint_as_float((u32)v << 16); }

__device__ __forceinline__ float sigm(float z) {
    float e = __builtin_amdgcn_exp2f(z * -1.44269504f);
    return __builtin_amdgcn_rcpf(1.0f + e);
}
__device__ __forceinline__ float tanhfast(float y) {
    float e = __builtin_amdgcn_exp2f(y * 2.88539008f);     // e^(2y)
    return 1.0f - 2.0f * __builtin_amdgcn_rcpf(1.0f + e);  // handles +/-inf saturation
}

__device__ __forceinline__ void bar_lgkm() {
    asm volatile("s_waitcnt lgkmcnt(0)" ::: "memory");
    __builtin_amdgcn_s_barrier();
    asm volatile("" ::: "memory");
}
__device__ __forceinline__ void bar_only() {
    asm volatile("" ::: "memory");
    __builtin_amdgcn_s_barrier();
    asm volatile("" ::: "memory");
}

#define GLD_LDS16(g, l) __builtin_amdgcn_global_load_lds( \
    (const __attribute__((address_space(1))) unsigned int*)(g), \
    (__attribute__((address_space(3))) unsigned int*)(l), 16, 0, 0)

// ---------------------------------------------------------------------------
// Generic K=256, N=256 GEMM (P1: f32 A in). Register-prefetched strips (R6).
// ---------------------------------------------------------------------------
__global__ __launch_bounds__(256, 2)
void gemm256(const void* __restrict__ Asrc, int a_f32, const u16* __restrict__ A2,
             const float* __restrict__ W, const float* __restrict__ b1,
             const float* __restrict__ b2, void* __restrict__ Cdst, int c_f32, int M)
{
    __shared__ u16 At[32 * LDP];
    const int tid  = threadIdx.x;
    const int lane = tid & 63, wv = tid >> 6;
    const int quad = lane >> 4, n16 = lane & 15;

    s16x8 bw[4][8];
    #pragma unroll
    for (int nt = 0; nt < 4; ++nt) {
        const int col = wv * 64 + nt * 16 + n16;
        #pragma unroll
        for (int kt = 0; kt < 8; ++kt) {
            const int kb0 = kt * 32 + quad * 8;
            s16x8 f;
            #pragma unroll
            for (int j = 0; j < 8; ++j) f[j] = (short)f2bf(W[(kb0 + j) * 256 + col]);
            bw[nt][kt] = f;
        }
    }

    const int arow = tid >> 3, kb = (tid & 7) * 32;
    float av[32];
    const int nstrip = M >> 5;
    const int stride = (int)gridDim.x;

    auto load_strip = [&](int ss) __attribute__((always_inline)) {
        const long base = (long)(ss * 32 + arow) * 256 + kb;
        if (a_f32) {
            const float4* p = (const float4*)((const float*)Asrc + base);
            #pragma unroll
            for (int i = 0; i < 8; ++i) {
                float4 v = p[i];
                av[i*4+0] = v.x; av[i*4+1] = v.y; av[i*4+2] = v.z; av[i*4+3] = v.w;
            }
        } else {
            const uint4* p = (const uint4*)((const u16*)Asrc + base);
            #pragma unroll
            for (int i = 0; i < 4; ++i) {
                uint4 v = p[i];
                av[i*8+0] = bflo(v.x); av[i*8+1] = bfhi(v.x);
                av[i*8+2] = bflo(v.y); av[i*8+3] = bfhi(v.y);
                av[i*8+4] = bflo(v.z); av[i*8+5] = bfhi(v.z);
                av[i*8+6] = bflo(v.w); av[i*8+7] = bfhi(v.w);
            }
            if (A2) {
                const uint4* q = (const uint4*)(A2 + base);
                #pragma unroll
                for (int i = 0; i < 4; ++i) {
                    uint4 v = q[i];
                    av[i*8+0] += bflo(v.x); av[i*8+1] += bfhi(v.x);
                    av[i*8+2] += bflo(v.y); av[i*8+3] += bfhi(v.y);
                    av[i*8+4] += bflo(v.z); av[i*8+5] += bfhi(v.z);
                    av[i*8+6] += bflo(v.w); av[i*8+7] += bfhi(v.w);
                }
            }
        }
    };

    int s = (int)blockIdx.x;
    if (s < nstrip) load_strip(s);

    for (; s < nstrip; ) {
        bar_only();
        {
            u16 tmp[32];
            #pragma unroll
            for (int i = 0; i < 32; ++i) tmp[i] = f2bf(av[i]);
            s16x8* dst = (s16x8*)&At[arow * LDP + kb];
            #pragma unroll
            for (int i = 0; i < 4; ++i) dst[i] = *(const s16x8*)&tmp[i * 8];
        }
        bar_lgkm();

        const int snext = s + stride;
        if (snext < nstrip) load_strip(snext);

        f32x4 acc[2][4];
        #pragma unroll
        for (int mt = 0; mt < 2; ++mt)
            #pragma unroll
            for (int nt = 0; nt < 4; ++nt) acc[mt][nt] = f32x4{0.f, 0.f, 0.f, 0.f};
        #pragma unroll
        for (int kt = 0; kt < 8; ++kt) {
            const int ko = kt * 32 + quad * 8;
            const s16x8 a0 = *(const s16x8*)&At[(n16) * LDP + ko];
            const s16x8 a1 = *(const s16x8*)&At[(16 + n16) * LDP + ko];
            #pragma unroll
            for (int nt = 0; nt < 4; ++nt) {
                acc[0][nt] = __builtin_amdgcn_mfma_f32_16x16x32_bf16(a0, bw[nt][kt], acc[0][nt], 0, 0, 0);
                acc[1][nt] = __builtin_amdgcn_mfma_f32_16x16x32_bf16(a1, bw[nt][kt], acc[1][nt], 0, 0, 0);
            }
        }

        #pragma unroll
        for (int nt = 0; nt < 4; ++nt) {
            const int col = wv * 64 + nt * 16 + n16;
            const float bias = b1[col] + (b2 ? b2[col] : 0.0f);
            #pragma unroll
            for (int mt = 0; mt < 2; ++mt) {
                const int row0 = s * 32 + mt * 16 + quad * 4;
                #pragma unroll
                for (int r = 0; r < 4; ++r) {
                    const float v = acc[mt][nt][r] + bias;
                    const long idx = (long)(row0 + r) * 256 + col;
                    if (c_f32) ((float*)Cdst)[idx] = v;
                    else       ((u16*)Cdst)[idx]   = f2bf(v);
                }
            }
        }
        s = snext;
    }
}

// ---------------------------------------------------------------------------
// P2 merged: 3 GEMMs (XX/XR/XU) in one launch, grid 1536 (matrix = bid>>9).
// A staged via global_load_lds (XOR-swizzled source), LDS double-buffered.
// ---------------------------------------------------------------------------
__global__ __launch_bounds__(256, 2)
void gemm_p2(const u16* __restrict__ X,
             const float* __restrict__ W0, const float* __restrict__ W1, const float* __restrict__ W2,
             const float* __restrict__ bA0, const float* __restrict__ bA1, const float* __restrict__ bA2,
             const float* __restrict__ bB1, const float* __restrict__ bB2,
             u16* __restrict__ C0, u16* __restrict__ C1, u16* __restrict__ C2)
{
    __shared__ u16 At[2][32 * 256];     // 2 x 16 KiB, linear
    const int tid  = threadIdx.x;
    const int lane = tid & 63, wv = tid >> 6;
    const int quad = lane >> 4, n16 = lane & 15;

    const int m  = (int)blockIdx.x >> 9;
    const int s0 = (int)blockIdx.x & 511;
    const float* W  = (m == 0) ? W0 : ((m == 1) ? W1 : W2);
    const float* b1 = (m == 0) ? bA0 : ((m == 1) ? bA1 : bA2);
    const float* b2 = (m == 0) ? (const float*)nullptr : ((m == 1) ? bB1 : bB2);
    u16* C = (m == 0) ? C0 : ((m == 1) ? C1 : C2);

    s16x8 bw[4][8];
    #pragma unroll
    for (int nt = 0; nt < 4; ++nt) {
        const int col = wv * 64 + nt * 16 + n16;
        #pragma unroll
        for (int kt = 0; kt < 8; ++kt) {
            const int kb0 = kt * 32 + quad * 8;
            s16x8 f;
            #pragma unroll
            for (int j = 0; j < 8; ++j) f[j] = (short)f2bf(W[(kb0 + j) * 256 + col]);
            bw[nt][kt] = f;
        }
    }

    u32 myL[4];
    #pragma unroll
    for (int r = 0; r < 4; ++r) {
        const u32 p = ((u32)(wv * 4 + r) * 64 + (u32)lane) * 16;
        myL[r] = p ^ (((p >> 9) & 7u) << 4);
    }
    const u32 key   = ((u32)(n16 & 7)) << 4;
    const u32 base0 = (u32)n16 * 512 + (u32)quad * 16;
    const u32 base1 = base0 + 16 * 512;

    {
        const char* src = (const char*)(X + (long)s0 * 32 * 256);
        #pragma unroll
        for (int r = 0; r < 4; ++r)
            GLD_LDS16(src + myL[r], (char*)&At[0][0] + (u32)(wv * 4 + r) * 1024);
    }

    int cur = 0;
    for (int s = s0; s < 2048; s += 512) {
        asm volatile("s_waitcnt vmcnt(0)" ::: "memory");
        bar_only();

        const int snext = s + 512;
        if (snext < 2048) {
            const char* src = (const char*)(X + (long)snext * 32 * 256);
            #pragma unroll
            for (int r = 0; r < 4; ++r)
                GLD_LDS16(src + myL[r], (char*)&At[cur ^ 1][0] + (u32)(wv * 4 + r) * 1024);
        }

        const char* atc = (const char*)&At[cur][0];
        f32x4 acc[2][4];
        #pragma unroll
        for (int mt = 0; mt < 2; ++mt)
            #pragma unroll
            for (int nt = 0; nt < 4; ++nt) acc[mt][nt] = f32x4{0.f, 0.f, 0.f, 0.f};
        #pragma unroll
        for (int kt = 0; kt < 8; ++kt) {
            const s16x8 a0 = *(const s16x8*)(atc + (((base0 + (u32)kt * 64) ^ key)));
            const s16x8 a1 = *(const s16x8*)(atc + (((base1 + (u32)kt * 64) ^ key)));
            #pragma unroll
            for (int nt = 0; nt < 4; ++nt) {
                acc[0][nt] = __builtin_amdgcn_mfma_f32_16x16x32_bf16(a0, bw[nt][kt], acc[0][nt], 0, 0, 0);
                acc[1][nt] = __builtin_amdgcn_mfma_f32_16x16x32_bf16(a1, bw[nt][kt], acc[1][nt], 0, 0, 0);
            }
        }

        #pragma unroll
        for (int nt = 0; nt < 4; ++nt) {
            const int col = wv * 64 + nt * 16 + n16;
            const float bias = b1[col] + (b2 ? b2[col] : 0.0f);
            #pragma unroll
            for (int mt = 0; mt < 2; ++mt) {
                const int row0 = s * 32 + mt * 16 + quad * 4;
                #pragma unroll
                for (int r = 0; r < 4; ++r) {
                    const float v = acc[mt][nt][r] + bias;
                    C[(long)(row0 + r) * 256 + col] = f2bf(v);
                }
            }
        }
        cur ^= 1;
    }
}

// ---------------------------------------------------------------------------
// F: out = Hf@Wo + Hb@Wo + Wo_b (f32 out). MFMA linearity removes the VALU
// unpack/add/repack; both bf16 operands staged via global_load_lds with the
// gemm_p2 swizzle. Single-buffered (32KB LDS): 2 blocks/CU cover the DMA.
// ---------------------------------------------------------------------------
__global__ __launch_bounds__(256, 2)
void gemm_f(const u16* __restrict__ Hf, const u16* __restrict__ Hb,
            const float* __restrict__ W, const float* __restrict__ bias,
            float* __restrict__ out)
{
    __shared__ u16 At[2][32 * 256];     // [mat] 2 x 16 KiB, linear
    const int tid  = threadIdx.x;
    const int lane = tid & 63, wv = tid >> 6;
    const int quad = lane >> 4, n16 = lane & 15;

    s16x8 bw[4][8];
    #pragma unroll
    for (int nt = 0; nt < 4; ++nt) {
        const int col = wv * 64 + nt * 16 + n16;
        #pragma unroll
        for (int kt = 0; kt < 8; ++kt) {
            const int kb0 = kt * 32 + quad * 8;
            s16x8 f;
            #pragma unroll
            for (int j = 0; j < 8; ++j) f[j] = (short)f2bf(W[(kb0 + j) * 256 + col]);
            bw[nt][kt] = f;
        }
    }

    u32 myL[4];
    #pragma unroll
    for (int r = 0; r < 4; ++r) {
        const u32 p = ((u32)(wv * 4 + r) * 64 + (u32)lane) * 16;
        myL[r] = p ^ (((p >> 9) & 7u) << 4);
    }
    const u32 key   = ((u32)(n16 & 7)) << 4;
    const u32 base0 = (u32)n16 * 512 + (u32)quad * 16;
    const u32 base1 = base0 + 16 * 512;

    auto stage = [&](int ss) __attribute__((always_inline)) {
        const char* f = (const char*)(Hf + (long)ss * 32 * 256);
        const char* b = (const char*)(Hb + (long)ss * 32 * 256);
        #pragma unroll
        for (int r = 0; r < 4; ++r)
            GLD_LDS16(f + myL[r], (char*)&At[0][0] + (u32)(wv * 4 + r) * 1024);
        #pragma unroll
        for (int r = 0; r < 4; ++r)
            GLD_LDS16(b + myL[r], (char*)&At[1][0] + (u32)(wv * 4 + r) * 1024);
    };

    const int s0 = (int)blockIdx.x;
    stage(s0);

    for (int s = s0; s < 2048; s += 512) {
        asm volatile("s_waitcnt vmcnt(0)" ::: "memory");
        bar_only();                              // DMA landed in all waves

        const char* atf = (const char*)&At[0][0];
        const char* atb = (const char*)&At[1][0];
        f32x4 acc[2][4];
        #pragma unroll
        for (int mt = 0; mt < 2; ++mt)
            #pragma unroll
            for (int nt = 0; nt < 4; ++nt) acc[mt][nt] = f32x4{0.f, 0.f, 0.f, 0.f};
        #pragma unroll
        for (int kt = 0; kt < 8; ++kt) {
            const s16x8 f0 = *(const s16x8*)(atf + (((base0 + (u32)kt * 64) ^ key)));
            const s16x8 f1 = *(const s16x8*)(atf + (((base1 + (u32)kt * 64) ^ key)));
            const s16x8 g0 = *(const s16x8*)(atb + (((base0 + (u32)kt * 64) ^ key)));
            const s16x8 g1 = *(const s16x8*)(atb + (((base1 + (u32)kt * 64) ^ key)));
            #pragma unroll
            for (int nt = 0; nt < 4; ++nt) {
                acc[0][nt] = __builtin_amdgcn_mfma_f32_16x16x32_bf16(f0, bw[nt][kt], acc[0][nt], 0, 0, 0);
                acc[1][nt] = __builtin_amdgcn_mfma_f32_16x16x32_bf16(f1, bw[nt][kt], acc[1][nt], 0, 0, 0);
                acc[0][nt] = __builtin_amdgcn_mfma_f32_16x16x32_bf16(g0, bw[nt][kt], acc[0][nt], 0, 0, 0);
                acc[1][nt] = __builtin_amdgcn_mfma_f32_16x16x32_bf16(g1, bw[nt][kt], acc[1][nt], 0, 0, 0);
            }
        }

        #pragma unroll
        for (int nt = 0; nt < 4; ++nt) {
            const int col = wv * 64 + nt * 16 + n16;
            const float bv = bias[col];
            #pragma unroll
            for (int mt = 0; mt < 2; ++mt) {
                const int row0 = s * 32 + mt * 16 + quad * 4;
                #pragma unroll
                for (int r = 0; r < 4; ++r)
                    out[(long)(row0 + r) * 256 + col] = acc[mt][nt][r] + bv;
            }
        }

        const int snext = s + 512;
        if (snext < 2048) {
            bar_only();                          // all waves' At reads done (WAR)
            stage(snext);
        }
    }
}

// ---------------------------------------------------------------------------
// Recurrence — EXACT R8 code (best measured: 462 us, absmax-neutral int8).
// 64 blocks x 512 threads. Wave w owns h-cols [w*32,w*32+32), both gates.
// mfma_i32_16x16x64_i8: 16 MFMAs + 4 ds_read_b128 per wave per step; h fp32
// in regs, int8 (scale 127, |h|<1 structural) in LDS; W per-column int8
// (one-time in-kernel quant). hb8 16B-aligned, parity stride 320B.
// One lgkm-only barrier per step; Hg store + x prefetch stay in flight.
// ---------------------------------------------------------------------------
__global__ __launch_bounds__(512, 2)
void gru_rec(const u16* __restrict__ XX, const u16* __restrict__ XR, const u16* __restrict__ XU,
             const float* __restrict__ Wr, const float* __restrict__ Wu,
             u16* __restrict__ Hf, u16* __restrict__ Hb)
{
    __shared__ __attribute__((aligned(16))) char hb8[2][2 * 320];  // [buf][parity*320+col]
    __shared__ float sdq[8][2][32];       // dequant scale [wave][gate][col]

    const int tid  = threadIdx.x;
    const int lane = tid & 63, wave = tid >> 6;
    const int quad = lane >> 4, n16 = lane & 15;
    const int wg  = blockIdx.x;
    const int dir = wg >> 5;             // 0 fwd, 1 bwd
    const int b0  = (wg & 31) * 2;       // two batches: b0, b0+1
    const int c0  = wave * 32;

    // ---- preload + per-column int8 quantize: aw[g][nt][kt] (B-operand) ----
    i32x4 aw[2][2][4];
    #pragma unroll
    for (int g = 0; g < 2; ++g) {
        const float* Wg = g ? Wu : Wr;
        #pragma unroll
        for (int nt = 0; nt < 2; ++nt) {
            const int col = c0 + nt * 16 + n16;
            float wv64[64];
            float amax = 0.f;
            #pragma unroll
            for (int kt = 0; kt < 4; ++kt)
                #pragma unroll
                for (int j = 0; j < 16; ++j) {
                    const float w = Wg[(kt * 64 + quad * 16 + j) * 256 + col];
                    wv64[kt * 16 + j] = w;
                    amax = fmaxf(amax, fabsf(w));
                }
            // column amax spans the 4 quads (lane ^16, ^32) -> butterfly max
            amax = fmaxf(amax, __shfl_xor(amax, 16));
            amax = fmaxf(amax, __shfl_xor(amax, 32));
            const float inv = 127.f / amax;
            #pragma unroll
            for (int kt = 0; kt < 4; ++kt) {
                u32 b[4];
                #pragma unroll
                for (int d = 0; d < 4; ++d) {
                    u32 v = 0;
                    #pragma unroll
                    for (int e = 0; e < 4; ++e) {
                        const int qi = (int)__builtin_rintf(wv64[kt * 16 + d * 4 + e] * inv);
                        v |= ((u32)(qi & 255u)) << (8 * e);
                    }
                    b[d] = v;
                }
                aw[g][nt][kt] = (i32x4){(int)b[0], (int)b[1], (int)b[2], (int)b[3]};
            }
            if (quad == 0) sdq[wave][g][nt * 16 + n16] = amax * (1.0f / 16129.f); // amax/127^2
        }
    }

    // elementwise identity: one (seq, col) per lane
    const int  eseq = lane >> 5;                 // 0..1  (acc reg index)
    const int  ecl  = lane & 31;                 // 0..31
    const int  ntb  = ecl >> 4;                  // which n-tile holds this col
    const int  gcol = c0 + ecl;                  // global h column
    const long xrow = (long)(b0 + eseq) * 1024;  // row base within [B*L]
    float hprev = 0.0f;

    for (int i = tid; i < 2 * 320; i += 512) hb8[0][i] = 0;   // h(0) = 0

    u16* const Hg = dir ? Hb : Hf;

    u16 cxx, cxr, cxu;
    {
        const long off = (xrow + (dir ? 1023 : 0)) * 256 + gcol;
        cxx = XX[off]; cxr = XR[off]; cxu = XU[off];
    }
    __syncthreads();
    const float srq = sdq[wave][0][ecl];
    const float suq = sdq[wave][1][ecl];

    auto stepbody = [&](int step, int pb) __attribute__((always_inline)) {
        const int t = dir ? 1023 - step : step;
        int sn = step + 1; if (sn > 1023) sn = 1023;
        const int tn = dir ? 1023 - sn : sn;

        // prefetch next step's x (full step of latency slack, counted vmcnt)
        const long offn = (xrow + tn) * 256 + gcol;
        const u16 nxx = XX[offn], nxr = XR[offn], nxu = XU[offn];

        // ---- int8 matvecs: 4 ds_read_b128 + 16 MFMAs ----
        const char* hin = &hb8[pb][0] + (n16 & 1) * 320;
        i32x4 a00 = (i32x4){0,0,0,0}, a01 = a00, a10 = a00, a11 = a00;
        #pragma unroll
        for (int kt = 0; kt < 4; ++kt) {
            const i32x4 hv = *(const i32x4*)(hin + kt * 64 + quad * 16);
            a00 = __builtin_amdgcn_mfma_i32_16x16x64_i8(hv, aw[0][0][kt], a00, 0, 0, 0);
            a01 = __builtin_amdgcn_mfma_i32_16x16x64_i8(hv, aw[0][1][kt], a01, 0, 0, 0);
            a10 = __builtin_amdgcn_mfma_i32_16x16x64_i8(hv, aw[1][0][kt], a10, 0, 0, 0);
            a11 = __builtin_amdgcn_mfma_i32_16x16x64_i8(hv, aw[1][1][kt], a11, 0, 0, 0);
        }

        // ---- in-lane select + dequant ----
        const int pri = ntb ? (eseq ? a01[1] : a01[0]) : (eseq ? a00[1] : a00[0]);
        const int pui = ntb ? (eseq ? a11[1] : a11[0]) : (eseq ? a10[1] : a10[0]);
        const float pr = (float)pri * srq;
        const float pu = (float)pui * suq;

        // ---- elementwise: exactly one (seq, col) per lane ----
        const float rr   = sigm(pr + bf2f(cxr));
        const float uu   = sigm(pu + bf2f(cxu));
        const float cand = tanhfast(rr * hprev + bf2f(cxx));
        hprev = cand + uu * (hprev - cand);

        // |hprev| < 1 -> rint(h*127) in [-127,127], no clamp needed
        hb8[pb ^ 1][eseq * 320 + gcol] = (char)(int)__builtin_rintf(hprev * 127.f);
        Hg[(xrow + t) * 256 + gcol]    = f2bf(hprev);   // persist bf16 (fire & forget)

        cxx = nxx; cxr = nxr; cxu = nxu;
        bar_lgkm();                                     // hb8[pb^1] visible; NO vmcnt drain
    };

    for (int sp = 0; sp < 512; ++sp) {
        stepbody(sp * 2,     0);
        stepbody(sp * 2 + 1, 1);
    }
}

// ---------------------------------------------------------------------------
extern "C" void kernel_launch(void* const* d_in, const int* in_sizes, int n_in,
                              void* d_out, int out_size, void* d_ws, size_t ws_size,
                              hipStream_t stream)
{
    const float* inputs = (const float*)d_in[0];
    const float* Wi_w = (const float*)d_in[1];
    const float* Wi_b = (const float*)d_in[2];
    const float* Wx_w = (const float*)d_in[3];
    const float* Wx_b = (const float*)d_in[4];
    const float* Ux_w = (const float*)d_in[5];
    const float* Ux_b = (const float*)d_in[6];
    const float* Rx_w = (const float*)d_in[7];
    const float* Rx_b = (const float*)d_in[8];
    const float* Wr_w = (const float*)d_in[9];
    const float* Wr_b = (const float*)d_in[10];
    const float* Wu_w = (const float*)d_in[11];
    const float* Wu_b = (const float*)d_in[12];
    const float* Wo_w = (const float*)d_in[13];
    const float* Wo_b = (const float*)d_in[14];

    const long E = 64L * 1024 * 256;
    u16* XX = (u16*)d_ws;
    u16* XR = XX + E;
    u16* XU = XR + E;
    u16* Hf = XU + E;      // also used as X (bf16) between P1 and P2 — dead before R writes it
    u16* Hb = Hf + E;
    u16* Xb = Hf;

    const int M = 64 * 1024;
    const dim3 gg(512), gb(256);

    // P1: X = inputs @ Wi + Wi_b
    hipLaunchKernelGGL(gemm256, gg, gb, 0, stream,
                       (const void*)inputs, 1, (const u16*)nullptr, Wi_w, Wi_b, (const float*)nullptr,
                       (void*)Xb, 0, M);
    // P2 (merged): XX = X@Wx + Wx_b ; XR = X@Ux + Ux_b + Wr_b ; XU = X@Rx + Rx_b + Wu_b
    hipLaunchKernelGGL(gemm_p2, dim3(1536), gb, 0, stream,
                       (const u16*)Xb,
                       Wx_w, Ux_w, Rx_w,
                       Wx_b, Ux_b, Rx_b,
                       Wr_b, Wu_b,
                       XX, XR, XU);
    // R: the sequential scan (both directions concurrently, 64 WGs)
    hipLaunchKernelGGL(gru_rec, dim3(64), dim3(512), 0, stream,
                       (const u16*)XX, (const u16*)XR, (const u16*)XU, Wr_w, Wu_w, Hf, Hb);
    // F: out = Hf@Wo + Hb@Wo + Wo_b  (MFMA-linearity, global_load_lds staging)
    hipLaunchKernelGGL(gemm_f, gg, gb, 0, stream,
                       (const u16*)Hf, (const u16*)Hb, Wo_w, Wo_b, (float*)d_out);
}